// Round 2
// baseline (191.330 us; speedup 1.0000x reference)
//
#include <hip/hip_runtime.h>
#include <stdint.h>

#define NORI   197
#define FRAMES 8
#define NTOK   1576
#define BATCH  8
#define NHEAD  12
#define CDIM   768
#define MG     204
#define TOKENS 12608

typedef _Float16 half8 __attribute__((ext_vector_type(8)));
typedef float floatx4 __attribute__((ext_vector_type(4)));

typedef const __attribute__((address_space(1))) void GPTR;
typedef __attribute__((address_space(3))) void LPTR;

__device__ __forceinline__ int gather_idx(int m) {
    if (m < 8) return m * NORI;
    int u = m - 8;
    int f, t;
    if (u < 100) { f = u / 25; t = u - f * 25; }
    else         { f = 4 + (u - 100) / 24; t = (u - 100) - (f - 4) * 24; }
    return f * NORI + 1 + f + 8 * t;
}
__device__ __forceinline__ int col_frame(int m) {  // m in [8,204)
    int u = m - 8;
    return (u < 100) ? (u / 25) : (4 + (u - 100) / 24);
}

// ---------------- fp32 -> fp16 cast of the WEIGHTS only ----------------
// R6: x is no longer pre-cast; gemm_qkv reg-stages A from fp32 x directly.
// Saves the 58 MB x roundtrip (~9 us of the old 11.5 us cast kernel).
__global__ __launch_bounds__(256) void cast_w(
    const float* __restrict__ qkvw, const float* __restrict__ projw,
    _Float16* __restrict__ out)
{
    const int n2 = 3 * CDIM * CDIM / 8, n3 = CDIM * CDIM / 8;
    int i = blockIdx.x * 256 + threadIdx.x;
    if (i >= n2 + n3) return;
    const float* src; int off;
    if (i < n2) { src = qkvw;  off = i; }
    else        { src = projw; off = i - n2; }
    float4 a = ((const float4*)src)[2 * off];
    float4 b = ((const float4*)src)[2 * off + 1];
    half8 o = { (_Float16)a.x, (_Float16)a.y, (_Float16)a.z, (_Float16)a.w,
                (_Float16)b.x, (_Float16)b.y, (_Float16)b.z, (_Float16)b.w };
    ((half8*)out)[i] = o;
}

// ---------------- MFMA GEMM body, BK=32, double-buffered, 32 KB LDS ----------------
// fp16-A path (proj): unchanged — 4 global_load_lds/iter, s_waitcnt vmcnt(4) lgkm(0),
// prefetch in flight across the barrier.
// fp32-A path (qkv, R6): A is reg-staged from fp32 x (2x float4 -> cvt -> ds_write_b128
// into the IDENTICAL LDS bytes global_load_lds produced); B stays on global_load_lds.
// Pipeline: A-regs for tile t+1 are loaded at iter t-1 (reg dbuf, statically indexed),
// so vmcnt(2) at iter top retires only the A-regs and leaves B(t) in flight; B(t) is
// retired by vmcnt(6) after issuing A(t+2)+B(t+1) — every load gets >= 1 iter of hiding.
#define LOADA(R, K)                                                            \
    do { _Pragma("unroll") for (int i = 0; i < 2; i++) {                       \
        R[i][0] = ((const float4*)(saf[i] + (K) * 32))[0];                     \
        R[i][1] = ((const float4*)(saf[i] + (K) * 32))[1]; } } while (0)
#define CVTWR(R, DST)                                                          \
    do { _Pragma("unroll") for (int i = 0; i < 2; i++) {                       \
        half8 h = { (_Float16)R[i][0].x, (_Float16)R[i][0].y,                  \
                    (_Float16)R[i][0].z, (_Float16)R[i][0].w,                  \
                    (_Float16)R[i][1].x, (_Float16)R[i][1].y,                  \
                    (_Float16)R[i][1].z, (_Float16)R[i][1].w };                \
        *(half8*)&DST[soff[i] + l * 8] = h; } } while (0)

template <int OUT_F32, int A_F32>
__device__ __forceinline__ void gemm_body(
    const void* __restrict__ Ain, const _Float16* __restrict__ W,
    const float* __restrict__ bias, void* __restrict__ Y,
    int M, int Woff, int ldY, int gather, int r0, int c0,
    _Float16* As0, _Float16* Bs0, _Float16* As1, _Float16* Bs1)
{
    const int tid = threadIdx.x;
    const int w = tid >> 6, l = tid & 63;
    const int wm = (w >> 1) * 64, wn = (w & 1) * 64;

    const _Float16* sa[2];
    const float* saf[2];
    const _Float16* sb[2];
    int soff[2];
#pragma unroll
    for (int i = 0; i < 2; i++) {
        int rt = w * 32 + i * 16 + (l >> 2);
        int cg = (l & 3) ^ ((l >> 3) & 3);       // swizzled global chunk
        int ra = min(r0 + rt, M - 1);
        if (gather) { int b = ra / MG; int m = ra - b * MG; ra = b * NTOK + gather_idx(m); }
        if (A_F32) saf[i] = (const float*)Ain + (size_t)ra * CDIM + cg * 8;
        else       sa[i]  = (const _Float16*)Ain + (size_t)ra * CDIM + cg * 8;
        sb[i] = W + (size_t)(Woff + c0 + rt) * CDIM + cg * 8;
        soff[i] = (w * 32 + i * 16) * 32;
    }

    float4 arA[2][2], arB[2][2];   // fp32-A reg double buffer (static idx after unroll)

    if (A_F32) {
        LOADA(arA, 0);                              // tile 0
        __builtin_amdgcn_s_waitcnt(0x0070);         // vmcnt(0)
        CVTWR(arA, As0);
        LOADA(arB, 1);                              // tile 1 -> regs (queue: A1 x4)
#pragma unroll
        for (int i = 0; i < 2; i++)                 // tile 0 B (queue: A1 x4, B0 x2)
            __builtin_amdgcn_global_load_lds((GPTR*)sb[i], (LPTR*)(Bs0 + soff[i]), 16, 0, 0);
    } else {
#pragma unroll
        for (int i = 0; i < 2; i++) {
            __builtin_amdgcn_global_load_lds((GPTR*)sa[i], (LPTR*)(As0 + soff[i]), 16, 0, 0);
            __builtin_amdgcn_global_load_lds((GPTR*)sb[i], (LPTR*)(Bs0 + soff[i]), 16, 0, 0);
        }
    }

    floatx4 acc[4][4] = {};
    const int fc = ((l >> 4) ^ ((l >> 1) & 3)) * 8;
    const int mrow = l & 15;

#pragma unroll
    for (int it = 0; it < 24; it++) {
        const _Float16* Ac = (it & 1) ? As1 : As0;
        const _Float16* Bc = (it & 1) ? Bs1 : Bs0;
        _Float16* An = (it & 1) ? As0 : As1;
        _Float16* Bn = (it & 1) ? Bs0 : Bs1;

        if (A_F32) {
            if (it < 23) {
                // retire A(it+1) regs only; B(it) stays in flight
                __builtin_amdgcn_s_waitcnt(0x0072);   // vmcnt(2) lgkm(0)
                if (it & 1) { CVTWR(arA, An); } else { CVTWR(arB, An); }
                if (it < 22) {
                    if (it & 1) { LOADA(arB, it + 2); } else { LOADA(arA, it + 2); }
                }
#pragma unroll
                for (int i = 0; i < 2; i++)
                    __builtin_amdgcn_global_load_lds((GPTR*)(sb[i] + (it + 1) * 32),
                                                     (LPTR*)(Bn + soff[i]), 16, 0, 0);
                // retire B(it) (+ lgkm(0) so our ds_writes are visible past the barrier)
                if (it < 22) __builtin_amdgcn_s_waitcnt(0x0076);  // vmcnt(6) lgkm(0)
                else         __builtin_amdgcn_s_waitcnt(0x0072);  // vmcnt(2) lgkm(0)
            } else {
                __builtin_amdgcn_s_waitcnt(0x0070);   // drain: vmcnt(0) lgkm(0)
            }
        } else {
            if (it < 23) {
                int kb = (it + 1) * 32;
#pragma unroll
                for (int i = 0; i < 2; i++) {
                    __builtin_amdgcn_global_load_lds((GPTR*)(sa[i] + kb), (LPTR*)(An + soff[i]), 16, 0, 0);
                    __builtin_amdgcn_global_load_lds((GPTR*)(sb[i] + kb), (LPTR*)(Bn + soff[i]), 16, 0, 0);
                }
                __builtin_amdgcn_s_waitcnt(0x0074);   // vmcnt(4) lgkm(0)
            } else {
                __builtin_amdgcn_s_waitcnt(0x0070);   // vmcnt(0) lgkm(0)
            }
        }
        __builtin_amdgcn_s_barrier();             // buf 'cur' collectively staged

        half8 af[4], bf[4];
#pragma unroll
        for (int t = 0; t < 4; t++) {
            af[t] = *(const half8*)&Ac[(wm + t * 16 + mrow) * 32 + fc];
            bf[t] = *(const half8*)&Bc[(wn + t * 16 + mrow) * 32 + fc];
        }
#pragma unroll
        for (int mt = 0; mt < 4; mt++)
#pragma unroll
            for (int nt = 0; nt < 4; nt++)
                acc[mt][nt] = __builtin_amdgcn_mfma_f32_16x16x32_f16(af[mt], bf[nt], acc[mt][nt], 0, 0, 0);

        __builtin_amdgcn_s_barrier();             // release 'cur' for overwrite
    }

#pragma unroll
    for (int nt = 0; nt < 4; nt++) {
        int col = c0 + wn + nt * 16 + (l & 15);
        float bv = bias ? bias[col] : 0.f;
#pragma unroll
        for (int mt = 0; mt < 4; mt++) {
#pragma unroll
            for (int r = 0; r < 4; r++) {
                int row = r0 + wm + mt * 16 + (l >> 4) * 4 + r;
                if (row < M) {
                    if (OUT_F32) ((float*)Y)[(size_t)row * ldY + col] = acc[mt][nt][r] + bv;
                    else ((_Float16*)Y)[(size_t)row * ldY + col] = (_Float16)acc[mt][nt][r];
                }
            }
        }
    }
}

// XCD-grouping remap: all 6 col-blocks of row-block rb get bx === rb (mod 8),
// so they land on one XCD. bx in [0,624): xcd = bx&7, j = bx>>3;
// rb = (j%13)*8 + xcd; cb = j/13. Dummies (rb >= 99) exit immediately.
__device__ __forceinline__ bool xcd_map(int bx, int nrb, int& rb, int& cb) {
    int xcd = bx & 7, j = bx >> 3;
    rb = (j % 13) * 8 + xcd;
    cb = j / 13;
    return rb < nrb;
}

// Q GEMM (624 padded blocks) + gathered-KV GEMM (156 blocks) in one dispatch.
// A operand read directly from fp32 x (R6). launch_bounds(256,3) protects the
// 3-blocks/CU residency the 780-block grid needs against the +32 VGPR reg buffer.
__global__ __launch_bounds__(256, 3) void gemm_qkv(
    const float* __restrict__ x, const _Float16* __restrict__ qkvwh,
    _Float16* __restrict__ Qh, _Float16* __restrict__ KVh)
{
    __shared__ __align__(16) _Float16 As0[128 * 32];
    __shared__ __align__(16) _Float16 Bs0[128 * 32];
    __shared__ __align__(16) _Float16 As1[128 * 32];
    __shared__ __align__(16) _Float16 Bs1[128 * 32];
    int bx = blockIdx.x;
    if (bx < 624) {
        int rb, cb;
        if (!xcd_map(bx, 99, rb, cb)) return;
        gemm_body<0, 1>(x, qkvwh, nullptr, Qh, TOKENS, 0, CDIM, 0,
                        rb * 128, cb * 128, As0, Bs0, As1, Bs1);
    } else {
        int b2 = bx - 624;
        gemm_body<0, 1>(x, qkvwh, nullptr, KVh, BATCH * MG, CDIM, 1536, 1,
                        (b2 / 12) * 128, (b2 % 12) * 128, As0, Bs0, As1, Bs1);
    }
}

__global__ __launch_bounds__(256) void gemm_proj(
    const _Float16* __restrict__ AOh, const _Float16* __restrict__ projwh,
    const float* __restrict__ bias, float* __restrict__ out)
{
    __shared__ __align__(16) _Float16 As0[128 * 32];
    __shared__ __align__(16) _Float16 Bs0[128 * 32];
    __shared__ __align__(16) _Float16 As1[128 * 32];
    __shared__ __align__(16) _Float16 Bs1[128 * 32];
    int rb, cb;
    if (!xcd_map(blockIdx.x, 99, rb, cb)) return;
    gemm_body<1, 0>(AOh, projwh, bias, out, TOKENS, 0, CDIM, 0,
                    rb * 128, cb * 128, As0, Bs0, As1, Bs1);
}

// ---------------- fused masked attention, MFMA ----------------
// block = (b,h) x 320 q-rows (5 row-tiles of 16 per wave). K/V staged ONCE.
// LDS = 26112 + 26624 + 27648 = 80384 B <= 81920 -> 2 blocks/CU.
// R6: s_setprio(1) around the MFMA clusters (T5; +4-7% on attn per m191 A/B).
__global__ __launch_bounds__(256, 2) void attn_mfma(
    const _Float16* __restrict__ Qh, const _Float16* __restrict__ KVh,
    _Float16* __restrict__ AOh)
{
    __shared__ __align__(16) _Float16 Ks[204 * 64];  // [row][chunk^(row&7)]
    __shared__ __align__(16) _Float16 Vt[64 * 208];
    __shared__ __align__(16) _Float16 Ps[64 * 216];  // wave w owns rows [w*16, +16)

    const int tid = threadIdx.x;
    const int bh = blockIdx.x;
    const int b = bh / NHEAD, h = bh - b * NHEAD;
    const int qc0 = blockIdx.y * 320;

    for (int e = tid; e < MG * 8; e += 256) {
        int row = e >> 3, c8 = e & 7;
        half8 v = *(const half8*)&KVh[(size_t)(b * MG + row) * 1536 + h * 64 + c8 * 8];
        *(half8*)&Ks[row * 64 + ((c8 ^ (row & 7)) * 8)] = v;
    }
    {
        const int d0 = (tid >> 5) * 8, lmp = tid & 31;
#pragma unroll
        for (int mo = 0; mo < 7; mo++) {
            int mp = mo * 32 + lmp;
            if (mp >= 208) continue;
            half8 v = {};
            if (mp < MG) v = *(const half8*)&KVh[(size_t)(b * MG + mp) * 1536 + 768 + h * 64 + d0];
#pragma unroll
            for (int j = 0; j < 8; j++) Vt[(d0 + j) * 208 + mp] = v[j];
        }
    }
    __syncthreads();

    const int w = tid >> 6, l = tid & 63;
    const int lm = l & 15, lq = l >> 4;

    int cf[13];
#pragma unroll
    for (int t = 0; t < 13; t++) {
        int col = t * 16 + lm;
        cf[t] = (col < 8) ? -1 : (col >= MG ? -2 : col_frame(col));
    }

    _Float16* Pw = &Ps[(w * 16) * 216];

    for (int t5 = 0; t5 < 5; t5++) {
        const int rb = qc0 + t5 * 64 + w * 16;
        if (rb >= NTOK) break;   // per-wave exit; no barriers below

        floatx4 acc[13] = {};
        const int qrowA = min(rb + lm, NTOK - 1);
        const _Float16* qbase = Qh + (size_t)(b * NTOK + qrowA) * CDIM + h * 64;
        __builtin_amdgcn_s_setprio(1);
#pragma unroll
        for (int ks = 0; ks < 64; ks += 32) {
            half8 aq = *(const half8*)(qbase + ks + lq * 8);
#pragma unroll
            for (int t = 0; t < 13; t++) {
                half8 bk = *(const half8*)&Ks[(t * 16 + lm) * 64 + (((ks >> 3) + lq) ^ (lm & 7)) * 8];
                acc[t] = __builtin_amdgcn_mfma_f32_16x16x32_f16(aq, bk, acc[t], 0, 0, 0);
            }
        }
        __builtin_amdgcn_s_setprio(0);

#pragma unroll
        for (int r = 0; r < 4; r++) {
            int qrow = min(rb + lq * 4 + r, NTOK - 1);
            int rf = qrow / NORI;
            float sv[13];
            float mx = -1e30f;
#pragma unroll
            for (int t = 0; t < 13; t++) {
                float s = acc[t][r] * 0.125f;
                s *= (cf[t] == -1 || cf[t] == rf) ? 1.f : 0.8f;
                if (cf[t] == -2) s = -1e30f;
                sv[t] = s;
                mx = fmaxf(mx, s);
            }
#pragma unroll
            for (int off = 1; off < 16; off <<= 1) mx = fmaxf(mx, __shfl_xor(mx, off, 64));
            float sum = 0.f;
#pragma unroll
            for (int t = 0; t < 13; t++) { sv[t] = __expf(sv[t] - mx); sum += sv[t]; }
#pragma unroll
            for (int off = 1; off < 16; off <<= 1) sum += __shfl_xor(sum, off, 64);
            float inv = 1.f / sum;
#pragma unroll
            for (int t = 0; t < 13; t++) acc[t][r] = sv[t] * inv;
        }

#pragma unroll
        for (int t = 0; t < 13; t++)
#pragma unroll
            for (int r = 0; r < 4; r++)
                Pw[(lq * 4 + r) * 216 + t * 16 + lm] = (_Float16)acc[t][r];

        floatx4 oacc[4] = {};
        const _Float16* prow = &Pw[lm * 216];
        __builtin_amdgcn_s_setprio(1);
#pragma unroll
        for (int ks = 0; ks < 192; ks += 32) {
            half8 ap = *(const half8*)(prow + ks + lq * 8);
#pragma unroll
            for (int t = 0; t < 4; t++) {
                half8 bv = *(const half8*)&Vt[(t * 16 + lm) * 208 + ks + lq * 8];
                oacc[t] = __builtin_amdgcn_mfma_f32_16x16x32_f16(ap, bv, oacc[t], 0, 0, 0);
            }
        }
        {
            typedef _Float16 half4v __attribute__((ext_vector_type(4)));
            half4v ap4 = *(const half4v*)(prow + 192 + lq * 4);
#pragma unroll
            for (int t = 0; t < 4; t++) {
                half4v bv4 = *(const half4v*)&Vt[(t * 16 + lm) * 208 + 192 + lq * 4];
                oacc[t] = __builtin_amdgcn_mfma_f32_16x16x16f16(ap4, bv4, oacc[t], 0, 0, 0);
            }
        }
        __builtin_amdgcn_s_setprio(0);

#pragma unroll
        for (int t = 0; t < 4; t++)
#pragma unroll
            for (int r = 0; r < 4; r++) {
                int qrow = rb + lq * 4 + r;
                if (qrow < NTOK)
                    AOh[(size_t)(b * NTOK + qrow) * CDIM + h * 64 + t * 16 + lm] = (_Float16)oacc[t][r];
            }
    }
}

extern "C" void kernel_launch(void* const* d_in, const int* in_sizes, int n_in,
                              void* d_out, int out_size, void* d_ws, size_t ws_size,
                              hipStream_t stream) {
    const float* x      = (const float*)d_in[0];
    const float* qkv_w  = (const float*)d_in[1];
    const float* proj_w = (const float*)d_in[2];
    const float* proj_b = (const float*)d_in[3];
    float* out = (float*)d_out;

    _Float16* qkvwh  = (_Float16*)d_ws;
    _Float16* projwh = qkvwh + (size_t)3 * CDIM * CDIM;
    _Float16* Qh     = projwh + (size_t)CDIM * CDIM;
    _Float16* KVh    = Qh + (size_t)TOKENS * CDIM;
    _Float16* AOh    = KVh + (size_t)(BATCH * MG) * 1536;

    dim3 blk(256);
    const int ncast = (3 * CDIM * CDIM + CDIM * CDIM) / 8;
    cast_w<<<dim3((ncast + 255) / 256), blk, 0, stream>>>(qkv_w, proj_w, qkvwh);

    gemm_qkv<<<dim3(624 + 156), blk, 0, stream>>>(x, qkvwh, Qh, KVh);

    attn_mfma<<<dim3(BATCH * NHEAD, 5), blk, 0, stream>>>(Qh, KVh, AOh);

    gemm_proj<<<dim3(624), blk, 0, stream>>>(AOh, projwh, proj_b, out);
}

// Round 4
// 187.688 us; speedup vs baseline: 1.0194x; 1.0194x over previous
//
#include <hip/hip_runtime.h>
#include <stdint.h>

#define NORI   197
#define FRAMES 8
#define NTOK   1576
#define BATCH  8
#define NHEAD  12
#define CDIM   768
#define MG     204
#define TOKENS 12608

typedef _Float16 half8 __attribute__((ext_vector_type(8)));
typedef float floatx4 __attribute__((ext_vector_type(4)));

typedef const __attribute__((address_space(1))) void GPTR;
typedef __attribute__((address_space(3))) void LPTR;

__device__ __forceinline__ int gather_idx(int m) {
    if (m < 8) return m * NORI;
    int u = m - 8;
    int f, t;
    if (u < 100) { f = u / 25; t = u - f * 25; }
    else         { f = 4 + (u - 100) / 24; t = (u - 100) - (f - 4) * 24; }
    return f * NORI + 1 + f + 8 * t;
}
__device__ __forceinline__ int col_frame(int m) {  // m in [8,204)
    int u = m - 8;
    return (u < 100) ? (u / 25) : (4 + (u - 100) / 24);
}

// ---------------- fused fp32 -> fp16 cast of x, qkv_w, proj_w (R0 baseline) --------
__global__ __launch_bounds__(256) void cast_all(
    const float* __restrict__ x, const float* __restrict__ qkvw,
    const float* __restrict__ projw, _Float16* __restrict__ out)
{
    const int n1 = TOKENS * CDIM / 8, n2 = 3 * CDIM * CDIM / 8, n3 = CDIM * CDIM / 8;
    int i = blockIdx.x * 256 + threadIdx.x;
    if (i >= n1 + n2 + n3) return;
    const float* src; int off;
    if (i < n1)           { src = x;     off = i; }
    else if (i < n1 + n2) { src = qkvw;  off = i - n1; }
    else                  { src = projw; off = i - n1 - n2; }
    float4 a = ((const float4*)src)[2 * off];
    float4 b = ((const float4*)src)[2 * off + 1];
    half8 o = { (_Float16)a.x, (_Float16)a.y, (_Float16)a.z, (_Float16)a.w,
                (_Float16)b.x, (_Float16)b.y, (_Float16)b.z, (_Float16)b.w };
    ((half8*)out)[i] = o;
}

// ---------------- MFMA GEMM body, 64x128 tile, BK=32, double-buffered, 24 KB LDS ----
// R4: baseline (R0) fp16 gload_lds inner loop, ONLY geometry changed 128->64 rows:
// A 1 stage-slot/wave, B 2 slots/wave -> 3 loads/iter, vmcnt(3) lgkm(0) before
// barrier1, prefetch of tile it+1 stays in flight across the barrier.
// sched_barrier(0) after barrier1 / before barrier2 pins the compiler: LLVM cannot
// see the global_load_lds->ds_read dependency, and raw s_barrier is not a compiler
// fence -- R3's marginal absmax failure (2.9e-3 on bit-identical arithmetic) is
// attributed to a hoisted ds_read; these pins make the staging barrier real.
// Grid: qkv 1182+312, proj 1182 => ~5.8 blocks/CU issued, 5 resident
// (launch_bounds(256,5), 24 KB LDS). R2 counters showed 128-tile latency-bound
// at ~3 blocks/CU (MfmaUtil 14%, Occ 20%, HBM 17%).
template <int OUT_F32>
__device__ __forceinline__ void gemm_body64(
    const _Float16* __restrict__ A, const _Float16* __restrict__ W,
    const float* __restrict__ bias, void* __restrict__ Y,
    int M, int Woff, int ldY, int gather, int r0, int c0,
    _Float16* As0, _Float16* Bs0, _Float16* As1, _Float16* Bs1)
{
    const int tid = threadIdx.x;
    const int w = tid >> 6, l = tid & 63;
    const int wm = (w >> 1) * 32, wn = (w & 1) * 64;
    const int cg = (l & 3) ^ ((l >> 3) & 3);     // swizzled global chunk

    // A staging: wave w stages rows [w*16, w*16+16) of the 64-row tile
    const _Float16* saA;
    {
        int rt = w * 16 + (l >> 2);
        int ra = min(r0 + rt, M - 1);
        if (gather) { int b = ra / MG; int m = ra - b * MG; ra = b * NTOK + gather_idx(m); }
        saA = A + (size_t)ra * CDIM + cg * 8;
    }
    const int soffA = (w * 16) * 32;

    // B staging: wave w stages rows [w*32, w*32+32) of the 128-col tile
    const _Float16* sb[2];
    int soffB[2];
#pragma unroll
    for (int i = 0; i < 2; i++) {
        int rt = w * 32 + i * 16 + (l >> 2);
        sb[i] = W + (size_t)(Woff + c0 + rt) * CDIM + cg * 8;
        soffB[i] = (w * 32 + i * 16) * 32;
    }

    // prologue: stage tile 0 into buf0
    __builtin_amdgcn_global_load_lds((GPTR*)saA, (LPTR*)(As0 + soffA), 16, 0, 0);
#pragma unroll
    for (int i = 0; i < 2; i++)
        __builtin_amdgcn_global_load_lds((GPTR*)sb[i], (LPTR*)(Bs0 + soffB[i]), 16, 0, 0);

    floatx4 acc[2][4] = {};
    const int fc = ((l >> 4) ^ ((l >> 1) & 3)) * 8;
    const int mrow = l & 15;
    const int lm = l & 15, lq = l >> 4;

#pragma unroll
    for (int it = 0; it < 24; it++) {
        const _Float16* Ac = (it & 1) ? As1 : As0;
        const _Float16* Bc = (it & 1) ? Bs1 : Bs0;
        _Float16* An = (it & 1) ? As0 : As1;
        _Float16* Bn = (it & 1) ? Bs0 : Bs1;

        if (it < 23) {
            int kb = (it + 1) * 32;
            __builtin_amdgcn_global_load_lds((GPTR*)(saA + kb), (LPTR*)(An + soffA), 16, 0, 0);
#pragma unroll
            for (int i = 0; i < 2; i++)
                __builtin_amdgcn_global_load_lds((GPTR*)(sb[i] + kb), (LPTR*)(Bn + soffB[i]), 16, 0, 0);
            __builtin_amdgcn_s_waitcnt(0x0073);   // vmcnt(3) lgkm(0): tile it's 3 loads done
        } else {
            __builtin_amdgcn_s_waitcnt(0x0070);   // vmcnt(0) lgkm(0)
        }
        __builtin_amdgcn_s_barrier();             // buf 'cur' collectively staged
        __builtin_amdgcn_sched_barrier(0);        // ds_reads must not hoist above barrier

        half8 af[2], bf[4];
#pragma unroll
        for (int t = 0; t < 2; t++)
            af[t] = *(const half8*)&Ac[(wm + t * 16 + mrow) * 32 + fc];
#pragma unroll
        for (int t = 0; t < 4; t++)
            bf[t] = *(const half8*)&Bc[(wn + t * 16 + mrow) * 32 + fc];
#pragma unroll
        for (int mt = 0; mt < 2; mt++)
#pragma unroll
            for (int nt = 0; nt < 4; nt++)
                acc[mt][nt] = __builtin_amdgcn_mfma_f32_16x16x32_f16(af[mt], bf[nt], acc[mt][nt], 0, 0, 0);

        __builtin_amdgcn_sched_barrier(0);        // ds_reads must not sink below release
        __builtin_amdgcn_s_barrier();             // release 'cur' for overwrite
    }

#pragma unroll
    for (int nt = 0; nt < 4; nt++) {
        int col = c0 + wn + nt * 16 + lm;
        float bv = bias ? bias[col] : 0.f;
#pragma unroll
        for (int mt = 0; mt < 2; mt++) {
#pragma unroll
            for (int r = 0; r < 4; r++) {
                int row = r0 + wm + mt * 16 + lq * 4 + r;
                if (row < M) {
                    if (OUT_F32) ((float*)Y)[(size_t)row * ldY + col] = acc[mt][nt][r] + bv;
                    else ((_Float16*)Y)[(size_t)row * ldY + col] = (_Float16)acc[mt][nt][r];
                }
            }
        }
    }
}

// Bijective XCD-chunked remap (m204 form): blocks are dispatched round-robin over
// 8 XCDs; remap so each XCD owns a contiguous chunk of workgroup ids.
__device__ __forceinline__ int xcd_chunk(int bid, int nwg) {
    int xcd = bid & 7, j = bid >> 3;
    int q = nwg >> 3, r = nwg & 7;
    int base = (xcd < r) ? xcd * (q + 1) : r * (q + 1) + (xcd - r) * q;
    return base + j;
}

// Q GEMM (1182 blocks, 197rb x 6cb) + gathered-KV GEMM (312 blocks, 26rb x 12cb).
__global__ __launch_bounds__(256, 5) void gemm_qkv(
    const _Float16* __restrict__ xh, const _Float16* __restrict__ qkvwh,
    _Float16* __restrict__ Qh, _Float16* __restrict__ KVh)
{
    __shared__ __align__(16) _Float16 As0[64 * 32];
    __shared__ __align__(16) _Float16 Bs0[128 * 32];
    __shared__ __align__(16) _Float16 As1[64 * 32];
    __shared__ __align__(16) _Float16 Bs1[128 * 32];
    int bx = blockIdx.x;
    if (bx < 1182) {
        int wg = xcd_chunk(bx, 1182);
        int rb = wg / 6, cb = wg - rb * 6;
        gemm_body64<0>(xh, qkvwh, nullptr, Qh, TOKENS, 0, CDIM, 0,
                       rb * 64, cb * 128, As0, Bs0, As1, Bs1);
    } else {
        int b2 = bx - 1182;
        int wg = xcd_chunk(b2, 312);
        int rb = wg / 12, cb = wg - rb * 12;
        gemm_body64<0>(xh, qkvwh, nullptr, KVh, BATCH * MG, CDIM, 1536, 1,
                       rb * 64, cb * 128, As0, Bs0, As1, Bs1);
    }
}

__global__ __launch_bounds__(256, 5) void gemm_proj(
    const _Float16* __restrict__ AOh, const _Float16* __restrict__ projwh,
    const float* __restrict__ bias, float* __restrict__ out)
{
    __shared__ __align__(16) _Float16 As0[64 * 32];
    __shared__ __align__(16) _Float16 Bs0[128 * 32];
    __shared__ __align__(16) _Float16 As1[64 * 32];
    __shared__ __align__(16) _Float16 Bs1[128 * 32];
    int wg = xcd_chunk(blockIdx.x, 1182);
    int rb = wg / 6, cb = wg - rb * 6;
    gemm_body64<1>(AOh, projwh, bias, out, TOKENS, 0, CDIM, 0,
                   rb * 64, cb * 128, As0, Bs0, As1, Bs1);
}

// ---------------- fused masked attention, MFMA ----------------
// block = (b,h) x 320 q-rows (5 row-tiles of 16 per wave). K/V staged ONCE.
// LDS = 26112 + 26624 + 27648 = 80384 B <= 81920 -> 2 blocks/CU.
// setprio(1) around the MFMA clusters (T5; verified passing in R2).
__global__ __launch_bounds__(256, 2) void attn_mfma(
    const _Float16* __restrict__ Qh, const _Float16* __restrict__ KVh,
    _Float16* __restrict__ AOh)
{
    __shared__ __align__(16) _Float16 Ks[204 * 64];  // [row][chunk^(row&7)]
    __shared__ __align__(16) _Float16 Vt[64 * 208];
    __shared__ __align__(16) _Float16 Ps[64 * 216];  // wave w owns rows [w*16, +16)

    const int tid = threadIdx.x;
    const int bh = blockIdx.x;
    const int b = bh / NHEAD, h = bh - b * NHEAD;
    const int qc0 = blockIdx.y * 320;

    for (int e = tid; e < MG * 8; e += 256) {
        int row = e >> 3, c8 = e & 7;
        half8 v = *(const half8*)&KVh[(size_t)(b * MG + row) * 1536 + h * 64 + c8 * 8];
        *(half8*)&Ks[row * 64 + ((c8 ^ (row & 7)) * 8)] = v;
    }
    {
        const int d0 = (tid >> 5) * 8, lmp = tid & 31;
#pragma unroll
        for (int mo = 0; mo < 7; mo++) {
            int mp = mo * 32 + lmp;
            if (mp >= 208) continue;
            half8 v = {};
            if (mp < MG) v = *(const half8*)&KVh[(size_t)(b * MG + mp) * 1536 + 768 + h * 64 + d0];
#pragma unroll
            for (int j = 0; j < 8; j++) Vt[(d0 + j) * 208 + mp] = v[j];
        }
    }
    __syncthreads();

    const int w = tid >> 6, l = tid & 63;
    const int lm = l & 15, lq = l >> 4;

    int cf[13];
#pragma unroll
    for (int t = 0; t < 13; t++) {
        int col = t * 16 + lm;
        cf[t] = (col < 8) ? -1 : (col >= MG ? -2 : col_frame(col));
    }

    _Float16* Pw = &Ps[(w * 16) * 216];

    for (int t5 = 0; t5 < 5; t5++) {
        const int rb = qc0 + t5 * 64 + w * 16;
        if (rb >= NTOK) break;   // per-wave exit; no barriers below

        floatx4 acc[13] = {};
        const int qrowA = min(rb + lm, NTOK - 1);
        const _Float16* qbase = Qh + (size_t)(b * NTOK + qrowA) * CDIM + h * 64;
        __builtin_amdgcn_s_setprio(1);
#pragma unroll
        for (int ks = 0; ks < 64; ks += 32) {
            half8 aq = *(const half8*)(qbase + ks + lq * 8);
#pragma unroll
            for (int t = 0; t < 13; t++) {
                half8 bk = *(const half8*)&Ks[(t * 16 + lm) * 64 + (((ks >> 3) + lq) ^ (lm & 7)) * 8];
                acc[t] = __builtin_amdgcn_mfma_f32_16x16x32_f16(aq, bk, acc[t], 0, 0, 0);
            }
        }
        __builtin_amdgcn_s_setprio(0);

#pragma unroll
        for (int r = 0; r < 4; r++) {
            int qrow = min(rb + lq * 4 + r, NTOK - 1);
            int rf = qrow / NORI;
            float sv[13];
            float mx = -1e30f;
#pragma unroll
            for (int t = 0; t < 13; t++) {
                float s = acc[t][r] * 0.125f;
                s *= (cf[t] == -1 || cf[t] == rf) ? 1.f : 0.8f;
                if (cf[t] == -2) s = -1e30f;
                sv[t] = s;
                mx = fmaxf(mx, s);
            }
#pragma unroll
            for (int off = 1; off < 16; off <<= 1) mx = fmaxf(mx, __shfl_xor(mx, off, 64));
            float sum = 0.f;
#pragma unroll
            for (int t = 0; t < 13; t++) { sv[t] = __expf(sv[t] - mx); sum += sv[t]; }
#pragma unroll
            for (int off = 1; off < 16; off <<= 1) sum += __shfl_xor(sum, off, 64);
            float inv = 1.f / sum;
#pragma unroll
            for (int t = 0; t < 13; t++) acc[t][r] = sv[t] * inv;
        }

#pragma unroll
        for (int t = 0; t < 13; t++)
#pragma unroll
            for (int r = 0; r < 4; r++)
                Pw[(lq * 4 + r) * 216 + t * 16 + lm] = (_Float16)acc[t][r];

        floatx4 oacc[4] = {};
        const _Float16* prow = &Pw[lm * 216];
        __builtin_amdgcn_s_setprio(1);
#pragma unroll
        for (int ks = 0; ks < 192; ks += 32) {
            half8 ap = *(const half8*)(prow + ks + lq * 8);
#pragma unroll
            for (int t = 0; t < 4; t++) {
                half8 bv = *(const half8*)&Vt[(t * 16 + lm) * 208 + ks + lq * 8];
                oacc[t] = __builtin_amdgcn_mfma_f32_16x16x32_f16(ap, bv, oacc[t], 0, 0, 0);
            }
        }
        {
            typedef _Float16 half4v __attribute__((ext_vector_type(4)));
            half4v ap4 = *(const half4v*)(prow + 192 + lq * 4);
#pragma unroll
            for (int t = 0; t < 4; t++) {
                half4v bv4 = *(const half4v*)&Vt[(t * 16 + lm) * 208 + 192 + lq * 4];
                oacc[t] = __builtin_amdgcn_mfma_f32_16x16x16f16(ap4, bv4, oacc[t], 0, 0, 0);
            }
        }
        __builtin_amdgcn_s_setprio(0);

#pragma unroll
        for (int t = 0; t < 4; t++)
#pragma unroll
            for (int r = 0; r < 4; r++) {
                int qrow = rb + lq * 4 + r;
                if (qrow < NTOK)
                    AOh[(size_t)(b * NTOK + qrow) * CDIM + h * 64 + t * 16 + lm] = (_Float16)oacc[t][r];
            }
    }
}

extern "C" void kernel_launch(void* const* d_in, const int* in_sizes, int n_in,
                              void* d_out, int out_size, void* d_ws, size_t ws_size,
                              hipStream_t stream) {
    const float* x      = (const float*)d_in[0];
    const float* qkv_w  = (const float*)d_in[1];
    const float* proj_w = (const float*)d_in[2];
    const float* proj_b = (const float*)d_in[3];
    float* out = (float*)d_out;

    _Float16* xh     = (_Float16*)d_ws;
    _Float16* qkvwh  = xh + (size_t)TOKENS * CDIM;
    _Float16* projwh = qkvwh + (size_t)3 * CDIM * CDIM;
    _Float16* Qh     = projwh + (size_t)CDIM * CDIM;
    _Float16* KVh    = Qh + (size_t)TOKENS * CDIM;
    _Float16* AOh    = KVh + (size_t)(BATCH * MG) * 1536;

    dim3 blk(256);
    const int ncast = (TOKENS * CDIM + 3 * CDIM * CDIM + CDIM * CDIM) / 8;
    cast_all<<<dim3((ncast + 255) / 256), blk, 0, stream>>>(x, qkv_w, proj_w, xh);

    gemm_qkv<<<dim3(1182 + 312), blk, 0, stream>>>(xh, qkvwh, Qh, KVh);

    attn_mfma<<<dim3(BATCH * NHEAD, 5), blk, 0, stream>>>(Qh, KVh, AOh);

    gemm_proj<<<dim3(1182), blk, 0, stream>>>(AOh, projwh, proj_b, out);
}